// Round 15
// baseline (453.676 us; speedup 1.0000x reference)
//
#include <hip/hip_runtime.h>

// VoxelHashTableFlowTraverse: 8-corner hash-grid lookup + trilinear blend.
// R15 = R14 (software-pipelined persistent main kernel) + polish:
//  - C8 32->12: per-(XCD,bin) occupancy is ~Poisson(3.8); the sq8 slice
//    drops 16MB->6MB per XCD (near-L2-resident; overflow path covers tail);
//  - heavy-bins-first processing: compact writes bins with >=40 queries
//    from the list front, small bins from the back -> persistent blocks
//    start on stragglers, smoothing the end-of-kernel tail;
//  - query-slot prefetch uses 16 lanes/segment (fits C8<=16).

#define TABLE_MASK ((1u << 20) - 1u)
#define FEAT_DIM 120
#define ROW_STRIDE 120            // floats per row == NCHUNK*4 (contiguous)
#define NROWS 75                  // 5 x 5 x 3 neighborhood rows
#define NCHUNK 30                 // 120 floats = 30 float4 per row
#define TOTCH (NROWS * NCHUNK)    // 2250 chunks per bin
#define NSLOT 5                   // ceil(2250 / 512)
#define NXCD 8
#define C8 12                     // per-XCD per-bin capacity (mean ~3.8)
#define BIGTHR 40                 // "heavy bin" threshold (queries)

// Bins: 4x4x2 voxels -> 32 x 64 x 16 = 32768 bins.
#define NBINS_X 32
#define NBINS_Y 64
#define NBINS_Z 16
#define NBINS (NBINS_X * NBINS_Y * NBINS_Z)

typedef float f4 __attribute__((ext_vector_type(4)));

__global__ __launch_bounds__(256) void zero_kernel(int* __restrict__ hist8) {
    const int i = blockIdx.x * blockDim.x + threadIdx.x;
    if (i < NXCD * NBINS + 3) hist8[i] = 0;  // +0 ovf, +1 nbig, +2 nsmall
}

// Single-pass binning with XCD-local counters (RMW at the issuing XCD's L2).
// Stores pre-divided grid coords {gx,gy,gz,bits(q)}.
__global__ __launch_bounds__(256) void bin_kernel(
    const float* __restrict__ qp, int* __restrict__ hist8,
    f4* __restrict__ sq8, f4* __restrict__ ovf, int Cr, int M)
{
    const int q = blockIdx.x * blockDim.x + threadIdx.x;
    if (q >= M) return;

    int xcd;
    asm volatile("s_getreg_b32 %0, hwreg(HW_REG_XCC_ID)" : "=s"(xcd));
    xcd &= (NXCD - 1);

    // Divide by 0.1f (not *10) to match reference rounding.
    const float gx = qp[3 * q + 0] / 0.1f;
    const float gy = qp[3 * q + 1] / 0.1f;
    const float gz = qp[3 * q + 2] / 0.1f;
    const int bx = (int)floorf(gx);
    const int by = (int)floorf(gy);
    const int bz = (int)floorf(gz);
    const int kx = ((bx + 32) >> 2) & (NBINS_X - 1);
    const int ky = ((by + 96) >> 2) & (NBINS_Y - 1);
    const int kz = (bz >> 1) & (NBINS_Z - 1);
    const int key = ((kx * NBINS_Y) + ky) * NBINS_Z + kz;

    const int pos = __hip_atomic_fetch_add(&hist8[xcd * NBINS + key], 1,
                                           __ATOMIC_RELAXED,
                                           __HIP_MEMORY_SCOPE_WORKGROUP);
    f4 s;
    s.x = gx; s.y = gy; s.z = gz; s.w = __int_as_float(q);
    if (pos < Cr) {
        sq8[((size_t)xcd * NBINS + key) * C8 + pos] = s;
    } else {
        const int o = atomicAdd(&hist8[NXCD * NBINS], 1);   // device scope, rare
        if (o < M) ovf[o] = s;
    }
}

// Compact: heavy bins from the front, light bins from the back.
__global__ __launch_bounds__(256) void compact_kernel(
    const int* __restrict__ hist8, int* __restrict__ nbig,
    int* __restrict__ nsmall, int* __restrict__ list)
{
    const int i = blockIdx.x * blockDim.x + threadIdx.x;
    if (i >= NBINS) return;
    int tot = 0;
#pragma unroll
    for (int s = 0; s < NXCD; ++s) tot += hist8[s * NBINS + i];
    if (tot >= BIGTHR) {
        list[atomicAdd(nbig, 1)] = i;
    } else if (tot > 0) {
        list[NBINS - 1 - atomicAdd(nsmall, 1)] = i;
    }
}

// Main: persistent blocks, software-pipelined (prefetch bin b+stride into
// registers while blending bin b); heavy bins processed first.
__global__ __launch_bounds__(512, 4) void voxel_trilinear_kernel(
    const f4*    __restrict__ sq8,     // [NXCD][NBINS][C8] padded bin slots
    const float* __restrict__ feat,    // [n_vox,120]
    const int*   __restrict__ table,   // [2^20]
    const int*   __restrict__ hist8,   // [NXCD][NBINS] bin counts
    const int*   __restrict__ nbigp,
    const int*   __restrict__ nsmallp,
    const int*   __restrict__ list,    // active bin ids (front=big, back=small)
    float*       __restrict__ out,     // [M,120]
    int Cr)
{
    __shared__ f4    sqL[NXCD * C8];            // 1.5 KB
    __shared__ float rows[NROWS * ROW_STRIDE];  // 36 KB

    const int t = threadIdx.x;
    const int nbig = *nbigp;
    const int nact = nbig + *nsmallp;
    const int stride = gridDim.x;

    if (blockIdx.x >= nact) return;

    auto binat = [&](int i) {
        return list[(i < nbig) ? i : (NBINS - 1 - (i - nbig))];
    };

    // ---- prefetch state (registers) ----
    f4   rreg[NSLOT];
    f4   qreg;
    bool qok = false;
    int  qdst = 0;
    int  total = 0;

    auto prefetch = [&](int wg) {
        // Counts (8 broadcast loads; every thread needs total).
        int c[8];
#pragma unroll
        for (int i = 0; i < 8; ++i) {
            int v = hist8[i * NBINS + wg];
            c[i] = (v > Cr) ? Cr : v;     // overflow handled by ovf_kernel
        }
        total = 0;
#pragma unroll
        for (int i = 0; i < 8; ++i) total += c[i];

        // Query slot (t<128): segment seg (16 lanes each, C8<=16).
        qok = false;
        if (t < 128) {
            const int seg = t >> 4, lane = t & 15;
            int p = 0;
#pragma unroll
            for (int i = 0; i < 8; ++i) p += (i < seg) ? c[i] : 0;
            if (lane < c[seg]) {
                qok = true;
                qdst = p + lane;
                qreg = sq8[((size_t)seg * NBINS + wg) * C8 + lane];
            }
        }

        // Rows: per-chunk redundant hash -> table -> feat chain (no LDS).
        const int binx = wg >> 10;
        const int biny = (wg >> 4) & 63;
        const int binz = wg & 15;
        const int vx0 = binx * 4 - 32;
        const int vy0 = biny * 4 - 96;
        const int vz0 = binz * 2;
#pragma unroll
        for (int s = 0; s < NSLOT; ++s) {
            const int idx = t + s * 512;
            f4 val = (f4)(0.0f);
            if (idx < TOTCH) {
                const int row = idx / NCHUNK;
                const int chunk = idx - row * NCHUNK;
                const int i = row / 15;          // x offset 0..4
                const int j = (row / 3) % 5;     // y offset 0..4
                const int k = row % 3;           // z offset 0..2
                const unsigned h = (unsigned)(vx0 + i) * 73856093u
                                 + (unsigned)(vy0 + j) * 19349669u
                                 + (unsigned)(vz0 + k) * 83492791u;
                const int v = table[h & TABLE_MASK];
                if (v >= 0)
                    val = *reinterpret_cast<const f4*>(
                        feat + (size_t)v * FEAT_DIM + chunk * 4);
            }
            rreg[s] = val;
        }
    };

    // Prologue: prefetch first bin.
    prefetch(binat(blockIdx.x));

    for (int bi = blockIdx.x; bi < nact; bi += stride) {
        __syncthreads();                 // previous blend done reading LDS

        // Stage prefetched registers into LDS.
#pragma unroll
        for (int s = 0; s < NSLOT; ++s) {
            const int idx = t + s * 512;
            if (idx < TOTCH)
                *reinterpret_cast<f4*>(rows + idx * 4) = rreg[s];
        }
        if (qok) sqL[qdst] = qreg;
        const int ct = total;            // save before prefetch overwrites
        __syncthreads();                 // staging visible

        // Prefetch next bin (loads fly under the blend below).
        const int nb = bi + stride;
        if (nb < nact) prefetch(binat(nb));

        // Blend: 16 lanes per query, 32 query-groups per block.
        const int group = t >> 4;
        const int l = t & 15;
        const int CX[8] = {0, 1, 0, 0, 1, 1, 0, 1};
        const int CY[8] = {0, 0, 1, 0, 1, 0, 1, 1};
        const int CZ[8] = {0, 0, 0, 1, 0, 1, 1, 1};

        for (int qs = group; qs < ct; qs += 32) {
            const f4 qv = sqL[qs];
            const float rx = qv.x - floorf(qv.x);
            const float ry = qv.y - floorf(qv.y);
            const float rz = qv.z - floorf(qv.z);
            const int q = __float_as_int(qv.w);
            const int lx = ((int)floorf(qv.x) + 32) & 3;
            const int ly = ((int)floorf(qv.y) + 96) & 3;
            const int lz = (int)floorf(qv.z) & 1;

            const float sx = 1.0f - rx, sy = 1.0f - ry, sz = 1.0f - rz;
            // Corner order matches reference.
            float w[8];
            w[0] = sx * sy * sz;
            w[1] = rx * sy * sz;
            w[2] = sx * ry * sz;
            w[3] = sx * sy * rz;
            w[4] = rx * ry * sz;
            w[5] = rx * sy * rz;
            w[6] = sx * ry * rz;
            w[7] = rx * ry * rz;

            f4 a0 = (f4)(0.0f), a1 = (f4)(0.0f);
#pragma unroll
            for (int k = 0; k < 8; ++k) {
                const int row = ((lx + CX[k]) * 5 + (ly + CY[k])) * 3 + (lz + CZ[k]);
                const float* rp = rows + row * ROW_STRIDE;
                const f4 fa = *reinterpret_cast<const f4*>(rp + l * 4);
                const f4 fb = *reinterpret_cast<const f4*>(rp + 56 + l * 4);
                a0 += fa * w[k];
                a1 += fb * w[k];
            }

            float* po = out + (size_t)q * FEAT_DIM;
            __builtin_nontemporal_store(a0, reinterpret_cast<f4*>(po + l * 4));
            if (l >= 2)
                __builtin_nontemporal_store(a1, reinterpret_cast<f4*>(po + 56 + l * 4));
        }
    }
}

// Overflow fixup: direct 16-lane gather per query (normally ~zero work).
__global__ __launch_bounds__(256) void ovf_kernel(
    const f4*    __restrict__ ovf,
    const int*   __restrict__ hist8,   // hist8[NXCD*NBINS] = ovf count
    const float* __restrict__ feat,
    const int*   __restrict__ table,
    float*       __restrict__ out,
    int M)
{
    int n = hist8[NXCD * NBINS];
    if (n > M) n = M;
    if (n == 0) return;

    const int nthreads = gridDim.x * 256;
    for (int i = blockIdx.x * 256 + threadIdx.x; i < n * 16; i += nthreads) {
        const int g = i >> 4;
        const int l = i & 15;
        const f4 qv = ovf[g];
        const float gx = qv.x, gy = qv.y, gz = qv.z;
        const int q = __float_as_int(qv.w);
        const float flx = floorf(gx), fly = floorf(gy), flz = floorf(gz);
        const float rx = gx - flx, ry = gy - fly, rz = gz - flz;
        const int bx = (int)flx, by = (int)fly, bz = (int)flz;

        const unsigned hx0 = (unsigned)bx * 73856093u;
        const unsigned hy0 = (unsigned)by * 19349669u;
        const unsigned hz0 = (unsigned)bz * 83492791u;
        const unsigned hx1 = hx0 + 73856093u;
        const unsigned hy1 = hy0 + 19349669u;
        const unsigned hz1 = hz0 + 83492791u;

        unsigned h[8];
        h[0] = (hx0 + hy0 + hz0) & TABLE_MASK;
        h[1] = (hx1 + hy0 + hz0) & TABLE_MASK;
        h[2] = (hx0 + hy1 + hz0) & TABLE_MASK;
        h[3] = (hx0 + hy0 + hz1) & TABLE_MASK;
        h[4] = (hx1 + hy1 + hz0) & TABLE_MASK;
        h[5] = (hx1 + hy0 + hz1) & TABLE_MASK;
        h[6] = (hx0 + hy1 + hz1) & TABLE_MASK;
        h[7] = (hx1 + hy1 + hz1) & TABLE_MASK;

        int vidx[8];
#pragma unroll
        for (int k = 0; k < 8; ++k) vidx[k] = table[h[k]];

        const float sxw = 1.0f - rx, syw = 1.0f - ry, szw = 1.0f - rz;
        float w[8];
        w[0] = sxw * syw * szw;
        w[1] = rx  * syw * szw;
        w[2] = sxw * ry  * szw;
        w[3] = sxw * syw * rz;
        w[4] = rx  * ry  * szw;
        w[5] = rx  * syw * rz;
        w[6] = sxw * ry  * rz;
        w[7] = rx  * ry  * rz;

        f4 a0 = (f4)(0.0f), a1 = (f4)(0.0f);
#pragma unroll
        for (int k = 0; k < 8; ++k) {
            const int v = vidx[k] >= 0 ? vidx[k] : 0;
            const float wk = vidx[k] >= 0 ? w[k] : 0.0f;
            const float* rp = feat + (size_t)v * FEAT_DIM;
            const f4 fa = *reinterpret_cast<const f4*>(rp + l * 4);
            const f4 fb = *reinterpret_cast<const f4*>(rp + 56 + l * 4);
            a0 += fa * wk;
            a1 += fb * wk;
        }

        float* po = out + (size_t)q * FEAT_DIM;
        __builtin_nontemporal_store(a0, reinterpret_cast<f4*>(po + l * 4));
        if (l >= 2)
            __builtin_nontemporal_store(a1, reinterpret_cast<f4*>(po + 56 + l * 4));
    }
}

extern "C" void kernel_launch(void* const* d_in, const int* in_sizes, int n_in,
                              void* d_out, int out_size, void* d_ws, size_t ws_size,
                              hipStream_t stream) {
    const float* qp    = (const float*)d_in[0];
    const float* feat  = (const float*)d_in[1];
    const int*   table = (const int*)d_in[2];
    float*       out   = (float*)d_out;

    const int M = in_sizes[0] / 3;

    // Workspace: hist8[NXCD*NBINS+3] (16B-pad) | list[NBINS] | ovf[M] | sq8
    const size_t histB = ((NXCD * NBINS + 3) * sizeof(int) + 15) & ~(size_t)15;
    const size_t listB = (NBINS * sizeof(int) + 15) & ~(size_t)15;
    int* hist8  = (int*)d_ws;
    int* nbig   = hist8 + NXCD * NBINS + 1;
    int* nsmall = hist8 + NXCD * NBINS + 2;
    int* list   = (int*)((char*)d_ws + histB);
    f4*  ovf    = (f4*)((char*)d_ws + histB + listB);
    f4*  sq8    = ovf + M;

    const size_t fixed = histB + listB + (size_t)M * 16;
    size_t cap = (ws_size > fixed)
               ? (ws_size - fixed) / ((size_t)NXCD * NBINS * 16) : 0;
    int Cr = (cap > C8) ? C8 : (int)cap;
    if (Cr < 1) Cr = 1;

    const int block = 256;
    zero_kernel<<<(NXCD * NBINS + 3 + block - 1) / block, block, 0, stream>>>(hist8);
    bin_kernel<<<(M + block - 1) / block, block, 0, stream>>>(qp, hist8, sq8, ovf, Cr, M);
    compact_kernel<<<(NBINS + block - 1) / block, block, 0, stream>>>(hist8, nbig, nsmall, list);
    voxel_trilinear_kernel<<<1024, 512, 0, stream>>>(sq8, feat, table, hist8,
                                                     nbig, nsmall, list, out, Cr);
    ovf_kernel<<<512, 256, 0, stream>>>(ovf, hist8, feat, table, out, M);
}

// Round 16
// 239.670 us; speedup vs baseline: 1.8929x; 1.8929x over previous
//
#include <hip/hip_runtime.h>

// VoxelHashTableFlowTraverse: 8-corner hash-grid lookup + trilinear blend.
// R16 = R14 exactly (C8=32 — R15's C8=12 sat below the per-(XCD,bin)
// Poisson(14) mean and spilled ~1/3 of queries to the scattered overflow
// path, 234->454us) + heavy-bins-first ordering (the one orthogonal R15
// lever that never got a fair test): compact writes bins with >=40 queries
// to the list front, light bins to the back; persistent blocks start on
// the stragglers, smoothing the end-of-kernel tail.

#define TABLE_MASK ((1u << 20) - 1u)
#define FEAT_DIM 120
#define ROW_STRIDE 120            // floats per row == NCHUNK*4 (contiguous)
#define NROWS 75                  // 5 x 5 x 3 neighborhood rows
#define NCHUNK 30                 // 120 floats = 30 float4 per row
#define TOTCH (NROWS * NCHUNK)    // 2250 chunks per bin
#define NSLOT 5                   // ceil(2250 / 512)
#define NXCD 8
#define C8 32                     // per-XCD per-bin capacity (Poisson(14) tail-safe)
#define BIGTHR 40                 // "heavy bin" threshold (queries)

// Bins: 4x4x2 voxels -> 32 x 64 x 16 = 32768 bins.
#define NBINS_X 32
#define NBINS_Y 64
#define NBINS_Z 16
#define NBINS (NBINS_X * NBINS_Y * NBINS_Z)

typedef float f4 __attribute__((ext_vector_type(4)));

__global__ __launch_bounds__(256) void zero_kernel(int* __restrict__ hist8) {
    const int i = blockIdx.x * blockDim.x + threadIdx.x;
    if (i < NXCD * NBINS + 3) hist8[i] = 0;  // +0 ovf, +1 nbig, +2 nsmall
}

// Single-pass binning with XCD-local counters (RMW at the issuing XCD's L2).
// Stores pre-divided grid coords {gx,gy,gz,bits(q)}.
__global__ __launch_bounds__(256) void bin_kernel(
    const float* __restrict__ qp, int* __restrict__ hist8,
    f4* __restrict__ sq8, f4* __restrict__ ovf, int Cr, int M)
{
    const int q = blockIdx.x * blockDim.x + threadIdx.x;
    if (q >= M) return;

    int xcd;
    asm volatile("s_getreg_b32 %0, hwreg(HW_REG_XCC_ID)" : "=s"(xcd));
    xcd &= (NXCD - 1);

    // Divide by 0.1f (not *10) to match reference rounding.
    const float gx = qp[3 * q + 0] / 0.1f;
    const float gy = qp[3 * q + 1] / 0.1f;
    const float gz = qp[3 * q + 2] / 0.1f;
    const int bx = (int)floorf(gx);
    const int by = (int)floorf(gy);
    const int bz = (int)floorf(gz);
    const int kx = ((bx + 32) >> 2) & (NBINS_X - 1);
    const int ky = ((by + 96) >> 2) & (NBINS_Y - 1);
    const int kz = (bz >> 1) & (NBINS_Z - 1);
    const int key = ((kx * NBINS_Y) + ky) * NBINS_Z + kz;

    const int pos = __hip_atomic_fetch_add(&hist8[xcd * NBINS + key], 1,
                                           __ATOMIC_RELAXED,
                                           __HIP_MEMORY_SCOPE_WORKGROUP);
    f4 s;
    s.x = gx; s.y = gy; s.z = gz; s.w = __int_as_float(q);
    if (pos < Cr) {
        sq8[((size_t)xcd * NBINS + key) * C8 + pos] = s;
    } else {
        const int o = atomicAdd(&hist8[NXCD * NBINS], 1);   // device scope, rare
        if (o < M) ovf[o] = s;
    }
}

// Compact: heavy bins from the front, light bins from the back.
__global__ __launch_bounds__(256) void compact_kernel(
    const int* __restrict__ hist8, int* __restrict__ nbig,
    int* __restrict__ nsmall, int* __restrict__ list)
{
    const int i = blockIdx.x * blockDim.x + threadIdx.x;
    if (i >= NBINS) return;
    int tot = 0;
#pragma unroll
    for (int s = 0; s < NXCD; ++s) tot += hist8[s * NBINS + i];
    if (tot >= BIGTHR) {
        list[atomicAdd(nbig, 1)] = i;
    } else if (tot > 0) {
        list[NBINS - 1 - atomicAdd(nsmall, 1)] = i;
    }
}

// Main: persistent blocks, software-pipelined (prefetch bin b+stride into
// registers while blending bin b); heavy bins processed first.
__global__ __launch_bounds__(512, 4) void voxel_trilinear_kernel(
    const f4*    __restrict__ sq8,     // [NXCD][NBINS][C8] padded bin slots
    const float* __restrict__ feat,    // [n_vox,120]
    const int*   __restrict__ table,   // [2^20]
    const int*   __restrict__ hist8,   // [NXCD][NBINS] bin counts
    const int*   __restrict__ nbigp,
    const int*   __restrict__ nsmallp,
    const int*   __restrict__ list,    // active bin ids (front=big, back=small)
    float*       __restrict__ out,     // [M,120]
    int Cr)
{
    __shared__ f4    sqL[NXCD * C8];            // 4 KB
    __shared__ float rows[NROWS * ROW_STRIDE];  // 36 KB

    const int t = threadIdx.x;
    const int nbig = *nbigp;
    const int nact = nbig + *nsmallp;
    const int stride = gridDim.x;

    if (blockIdx.x >= nact) return;

    auto binat = [&](int i) {
        return list[(i < nbig) ? i : (NBINS - 1 - (i - nbig))];
    };

    // ---- prefetch state (registers) ----
    f4   rreg[NSLOT];
    f4   qreg;
    bool qok = false;
    int  qdst = 0;
    int  total = 0;

    auto prefetch = [&](int wg) {
        // Counts (8 broadcast loads; every thread needs total).
        int c[8];
#pragma unroll
        for (int i = 0; i < 8; ++i) {
            int v = hist8[i * NBINS + wg];
            c[i] = (v > Cr) ? Cr : v;     // overflow handled by ovf_kernel
        }
        total = 0;
#pragma unroll
        for (int i = 0; i < 8; ++i) total += c[i];

        // Query slot (t<256): segment seg (32 lanes each, C8<=32).
        qok = false;
        if (t < 256) {
            const int seg = t >> 5, lane = t & 31;
            int p = 0;
#pragma unroll
            for (int i = 0; i < 8; ++i) p += (i < seg) ? c[i] : 0;
            if (lane < c[seg]) {
                qok = true;
                qdst = p + lane;
                qreg = sq8[((size_t)seg * NBINS + wg) * C8 + lane];
            }
        }

        // Rows: per-chunk redundant hash -> table -> feat chain (no LDS).
        const int binx = wg >> 10;
        const int biny = (wg >> 4) & 63;
        const int binz = wg & 15;
        const int vx0 = binx * 4 - 32;
        const int vy0 = biny * 4 - 96;
        const int vz0 = binz * 2;
#pragma unroll
        for (int s = 0; s < NSLOT; ++s) {
            const int idx = t + s * 512;
            f4 val = (f4)(0.0f);
            if (idx < TOTCH) {
                const int row = idx / NCHUNK;
                const int chunk = idx - row * NCHUNK;
                const int i = row / 15;          // x offset 0..4
                const int j = (row / 3) % 5;     // y offset 0..4
                const int k = row % 3;           // z offset 0..2
                const unsigned h = (unsigned)(vx0 + i) * 73856093u
                                 + (unsigned)(vy0 + j) * 19349669u
                                 + (unsigned)(vz0 + k) * 83492791u;
                const int v = table[h & TABLE_MASK];
                if (v >= 0)
                    val = *reinterpret_cast<const f4*>(
                        feat + (size_t)v * FEAT_DIM + chunk * 4);
            }
            rreg[s] = val;
        }
    };

    // Prologue: prefetch first bin.
    prefetch(binat(blockIdx.x));

    for (int bi = blockIdx.x; bi < nact; bi += stride) {
        __syncthreads();                 // previous blend done reading LDS

        // Stage prefetched registers into LDS.
#pragma unroll
        for (int s = 0; s < NSLOT; ++s) {
            const int idx = t + s * 512;
            if (idx < TOTCH)
                *reinterpret_cast<f4*>(rows + idx * 4) = rreg[s];
        }
        if (qok) sqL[qdst] = qreg;
        const int ct = total;            // save before prefetch overwrites
        __syncthreads();                 // staging visible

        // Prefetch next bin (loads fly under the blend below).
        const int nb = bi + stride;
        if (nb < nact) prefetch(binat(nb));

        // Blend: 16 lanes per query, 32 query-groups per block.
        const int group = t >> 4;
        const int l = t & 15;
        const int CX[8] = {0, 1, 0, 0, 1, 1, 0, 1};
        const int CY[8] = {0, 0, 1, 0, 1, 0, 1, 1};
        const int CZ[8] = {0, 0, 0, 1, 0, 1, 1, 1};

        for (int qs = group; qs < ct; qs += 32) {
            const f4 qv = sqL[qs];
            const float rx = qv.x - floorf(qv.x);
            const float ry = qv.y - floorf(qv.y);
            const float rz = qv.z - floorf(qv.z);
            const int q = __float_as_int(qv.w);
            const int lx = ((int)floorf(qv.x) + 32) & 3;
            const int ly = ((int)floorf(qv.y) + 96) & 3;
            const int lz = (int)floorf(qv.z) & 1;

            const float sx = 1.0f - rx, sy = 1.0f - ry, sz = 1.0f - rz;
            // Corner order matches reference.
            float w[8];
            w[0] = sx * sy * sz;
            w[1] = rx * sy * sz;
            w[2] = sx * ry * sz;
            w[3] = sx * sy * rz;
            w[4] = rx * ry * sz;
            w[5] = rx * sy * rz;
            w[6] = sx * ry * rz;
            w[7] = rx * ry * rz;

            f4 a0 = (f4)(0.0f), a1 = (f4)(0.0f);
#pragma unroll
            for (int k = 0; k < 8; ++k) {
                const int row = ((lx + CX[k]) * 5 + (ly + CY[k])) * 3 + (lz + CZ[k]);
                const float* rp = rows + row * ROW_STRIDE;
                const f4 fa = *reinterpret_cast<const f4*>(rp + l * 4);
                const f4 fb = *reinterpret_cast<const f4*>(rp + 56 + l * 4);
                a0 += fa * w[k];
                a1 += fb * w[k];
            }

            float* po = out + (size_t)q * FEAT_DIM;
            __builtin_nontemporal_store(a0, reinterpret_cast<f4*>(po + l * 4));
            if (l >= 2)
                __builtin_nontemporal_store(a1, reinterpret_cast<f4*>(po + 56 + l * 4));
        }
    }
}

// Overflow fixup: direct 16-lane gather per query (normally ~zero work).
__global__ __launch_bounds__(256) void ovf_kernel(
    const f4*    __restrict__ ovf,
    const int*   __restrict__ hist8,   // hist8[NXCD*NBINS] = ovf count
    const float* __restrict__ feat,
    const int*   __restrict__ table,
    float*       __restrict__ out,
    int M)
{
    int n = hist8[NXCD * NBINS];
    if (n > M) n = M;
    if (n == 0) return;

    const int nthreads = gridDim.x * 256;
    for (int i = blockIdx.x * 256 + threadIdx.x; i < n * 16; i += nthreads) {
        const int g = i >> 4;
        const int l = i & 15;
        const f4 qv = ovf[g];
        const float gx = qv.x, gy = qv.y, gz = qv.z;
        const int q = __float_as_int(qv.w);
        const float flx = floorf(gx), fly = floorf(gy), flz = floorf(gz);
        const float rx = gx - flx, ry = gy - fly, rz = gz - flz;
        const int bx = (int)flx, by = (int)fly, bz = (int)flz;

        const unsigned hx0 = (unsigned)bx * 73856093u;
        const unsigned hy0 = (unsigned)by * 19349669u;
        const unsigned hz0 = (unsigned)bz * 83492791u;
        const unsigned hx1 = hx0 + 73856093u;
        const unsigned hy1 = hy0 + 19349669u;
        const unsigned hz1 = hz0 + 83492791u;

        unsigned h[8];
        h[0] = (hx0 + hy0 + hz0) & TABLE_MASK;
        h[1] = (hx1 + hy0 + hz0) & TABLE_MASK;
        h[2] = (hx0 + hy1 + hz0) & TABLE_MASK;
        h[3] = (hx0 + hy0 + hz1) & TABLE_MASK;
        h[4] = (hx1 + hy1 + hz0) & TABLE_MASK;
        h[5] = (hx1 + hy0 + hz1) & TABLE_MASK;
        h[6] = (hx0 + hy1 + hz1) & TABLE_MASK;
        h[7] = (hx1 + hy1 + hz1) & TABLE_MASK;

        int vidx[8];
#pragma unroll
        for (int k = 0; k < 8; ++k) vidx[k] = table[h[k]];

        const float sxw = 1.0f - rx, syw = 1.0f - ry, szw = 1.0f - rz;
        float w[8];
        w[0] = sxw * syw * szw;
        w[1] = rx  * syw * szw;
        w[2] = sxw * ry  * szw;
        w[3] = sxw * syw * rz;
        w[4] = rx  * ry  * szw;
        w[5] = rx  * syw * rz;
        w[6] = sxw * ry  * rz;
        w[7] = rx  * ry  * rz;

        f4 a0 = (f4)(0.0f), a1 = (f4)(0.0f);
#pragma unroll
        for (int k = 0; k < 8; ++k) {
            const int v = vidx[k] >= 0 ? vidx[k] : 0;
            const float wk = vidx[k] >= 0 ? w[k] : 0.0f;
            const float* rp = feat + (size_t)v * FEAT_DIM;
            const f4 fa = *reinterpret_cast<const f4*>(rp + l * 4);
            const f4 fb = *reinterpret_cast<const f4*>(rp + 56 + l * 4);
            a0 += fa * wk;
            a1 += fb * wk;
        }

        float* po = out + (size_t)q * FEAT_DIM;
        __builtin_nontemporal_store(a0, reinterpret_cast<f4*>(po + l * 4));
        if (l >= 2)
            __builtin_nontemporal_store(a1, reinterpret_cast<f4*>(po + 56 + l * 4));
    }
}

extern "C" void kernel_launch(void* const* d_in, const int* in_sizes, int n_in,
                              void* d_out, int out_size, void* d_ws, size_t ws_size,
                              hipStream_t stream) {
    const float* qp    = (const float*)d_in[0];
    const float* feat  = (const float*)d_in[1];
    const int*   table = (const int*)d_in[2];
    float*       out   = (float*)d_out;

    const int M = in_sizes[0] / 3;

    // Workspace: hist8[NXCD*NBINS+3] (16B-pad) | list[NBINS] | ovf[M] | sq8
    const size_t histB = ((NXCD * NBINS + 3) * sizeof(int) + 15) & ~(size_t)15;
    const size_t listB = (NBINS * sizeof(int) + 15) & ~(size_t)15;
    int* hist8  = (int*)d_ws;
    int* nbig   = hist8 + NXCD * NBINS + 1;
    int* nsmall = hist8 + NXCD * NBINS + 2;
    int* list   = (int*)((char*)d_ws + histB);
    f4*  ovf    = (f4*)((char*)d_ws + histB + listB);
    f4*  sq8    = ovf + M;

    const size_t fixed = histB + listB + (size_t)M * 16;
    size_t cap = (ws_size > fixed)
               ? (ws_size - fixed) / ((size_t)NXCD * NBINS * 16) : 0;
    int Cr = (cap > C8) ? C8 : (int)cap;
    if (Cr < 1) Cr = 1;

    const int block = 256;
    zero_kernel<<<(NXCD * NBINS + 3 + block - 1) / block, block, 0, stream>>>(hist8);
    bin_kernel<<<(M + block - 1) / block, block, 0, stream>>>(qp, hist8, sq8, ovf, Cr, M);
    compact_kernel<<<(NBINS + block - 1) / block, block, 0, stream>>>(hist8, nbig, nsmall, list);
    voxel_trilinear_kernel<<<1024, 512, 0, stream>>>(sq8, feat, table, hist8,
                                                     nbig, nsmall, list, out, Cr);
    ovf_kernel<<<512, 256, 0, stream>>>(ovf, hist8, feat, table, out, M);
}